// Round 7
// baseline (176.407 us; speedup 1.0000x reference)
//
#include <hip/hip_runtime.h>

// CIN forward: B=2048, F=32, DIM=64, layers (128,128)
// out[b, 0:64]   = sum_d relu(W0 @ z0 + b0)[64:128, d]
// out[b, 64:192] = sum_d relu(W1 @ z1 + b1)[0:128, d]
// z0[h*32+m, d] = x[h,d]*x[m,d];  z1[h*32+m, d] = h1[h,d]*x[m,d]
//
// R7: W-fetch-BW wall fix. Each wave: 64 rows x 64 cols x 2 BATCHES
// (A-frag feeds 4 MFMAs, halves W bytes/MFMA). 4 batches/block, grid 512 =
// 2 blocks/CU, 2 waves/SIMD (acc=128 AGPR). Distance-1 register prefetch.

#define K0 1024
#define K1 2048
#define OUTC 192
#define L0_ELEMS (128 * K0)      // 131072
#define L1_ELEMS (128 * K1)      // 262144

typedef _Float16 v8h  __attribute__((ext_vector_type(8)));
typedef _Float16 v2h  __attribute__((ext_vector_type(2)));
typedef float    v16f __attribute__((ext_vector_type(16)));

// Swizzled W (f16): frag f = ks*256 + rt4*64 + oct*32 + l31 holds
//   W[rt4*32 + l31][ks*16 + oct*8 + j], j=0..7
// Coalesced-read converter: thread t copies source elems i=t*8..t*8+7.
__global__ void convert_w_kernel(const float* __restrict__ W0,
                                 const float* __restrict__ W1,
                                 _Float16* __restrict__ wsw) {
    size_t i = ((size_t)blockIdx.x * blockDim.x + threadIdx.x) * 8;
    if (i >= (size_t)(L0_ELEMS + L1_ELEMS)) return;
    const float* src;
    _Float16* dstbase;
    int K, local;
    if (i < L0_ELEMS) {
        K = K0; src = W0; dstbase = wsw; local = (int)i;
    } else {
        K = K1; src = W1; dstbase = wsw + L0_ELEMS; local = (int)(i - L0_ELEMS);
    }
    int row = local / K, k = local % K;
    int ks = k >> 4, oct = (k >> 3) & 1;
    int frag = ks * 256 + (row >> 5) * 64 + oct * 32 + (row & 31);
    const float* s = src + (size_t)row * K + k;
    _Float16* d = dstbase + (size_t)frag * 8;
    #pragma unroll
    for (int j = 0; j < 8; ++j) d[j] = (_Float16)s[j];
}

// duplicate a u16 f16 scalar into all 8 elems of a v8h (1 VALU: lshl_or)
__device__ __forceinline__ v8h dupscalar(uint32_t u) {
    uint32_t pair = (u << 16) | u;
    v2h p = __builtin_bit_cast(v2h, pair);
    return __builtin_shufflevector(p, p, 0, 1, 0, 1, 0, 1, 0, 1);
}

#define MFMA32(A, B, C) __builtin_amdgcn_mfma_f32_32x32x16_f16((A), (B), (C), 0, 0, 0)

__global__ __launch_bounds__(256, 2) void cin_kernel(
    const float* __restrict__ X,      // (B, 32, 64) fp32
    const float* __restrict__ b0,     // (128,)
    const float* __restrict__ b1,     // (128,)
    const _Float16* __restrict__ Wsw, // swizzled W0 | W1 (f16)
    float* __restrict__ out)          // (B, 192) fp32
{
    __shared__ uint16_t xS[4][2048];   // x[m][d] f16 bits, 16 KB
    __shared__ uint16_t h1S[4][4096];  // h1[h][d] f16 bits, 32 KB; xT(pitch40) overlay at init
    __shared__ float biasLds[256];     // b0 | b1

    const int tid  = threadIdx.x;
    const int wave = tid >> 6;
    const int lane = tid & 63;
    const int rw   = wave & 1;    // row-half (0: rows 0-63, 1: rows 64-127)
    const int bp   = wave >> 1;   // batch-pair: local batches bp*2, bp*2+1
    const int lb0  = bp * 2;
    const int l31  = lane & 31;
    const int hi   = lane >> 5;   // k-octet selector
    const size_t bb = (size_t)blockIdx.x * 4;

    if (tid < 128) biasLds[tid] = b0[tid];
    else           biasLds[tid] = b1[tid - 128];

    // ---- stage x: xT (f16 pitch-40, overlaid in h1S) + xS (u16) ----
    const float* xsrc = X + bb * 2048;
    for (int i = tid; i < 8192; i += 256) {
        int bby = i >> 11, loc = i & 2047;
        int m = loc >> 6, d = loc & 63;
        _Float16 h = (_Float16)xsrc[i];
        ((_Float16*)&h1S[bby][0])[d * 40 + m] = h;
        xS[bby][m * 64 + d] = __builtin_bit_cast(uint16_t, h);
    }
    __syncthreads();

    // K-invariant B vector parts: xv[lb][c][p] = x_{lb}[m = p*16+hi*8 .. +7][d = c*32+l31]
    v8h xv[2][2][2];
    #pragma unroll
    for (int lb = 0; lb < 2; ++lb) {
        const _Float16* xT = (const _Float16*)&h1S[lb0 + lb][0];
        #pragma unroll
        for (int c = 0; c < 2; ++c)
            #pragma unroll
            for (int p = 0; p < 2; ++p)
                xv[lb][c][p] = *(const v8h*)&xT[(c * 32 + l31) * 40 + p * 16 + hi * 8];
    }
    __syncthreads();  // xv reads complete before h1S overlay is rewritten

    v16f acc[2][2][2];  // [lb][rt][c]
    #pragma unroll
    for (int lb = 0; lb < 2; ++lb)
        #pragma unroll
        for (int rt = 0; rt < 2; ++rt)
            #pragma unroll
            for (int c = 0; c < 2; ++c) acc[lb][rt][c] = (v16f)0.0f;

    // ================= layer 0 (H=32) =================
    {
        const _Float16* Wp = Wsw + (size_t)rw * 1024 + (size_t)lane * 8;
        const uint16_t* xp0 = &xS[lb0][0];
        const uint16_t* xp1 = &xS[lb0 + 1][0];
        v8h na00 = *(const v8h*)(Wp);
        v8h na10 = *(const v8h*)(Wp + 512);
        v8h na01 = *(const v8h*)(Wp + 2048);
        v8h na11 = *(const v8h*)(Wp + 2560);
        uint32_t nu00 = xp0[l31], nu01 = xp0[32 + l31];
        uint32_t nu10 = xp1[l31], nu11 = xp1[32 + l31];
        #pragma unroll 2
        for (int h = 0; h < 31; ++h) {
            v8h a00 = na00, a10 = na10, a01 = na01, a11 = na11;
            uint32_t u00 = nu00, u01 = nu01, u10 = nu10, u11 = nu11;
            Wp += 4096;
            na00 = *(const v8h*)(Wp);
            na10 = *(const v8h*)(Wp + 512);
            na01 = *(const v8h*)(Wp + 2048);
            na11 = *(const v8h*)(Wp + 2560);
            nu00 = xp0[(h + 1) * 64 + l31];
            nu01 = xp0[(h + 1) * 64 + 32 + l31];
            nu10 = xp1[(h + 1) * 64 + l31];
            nu11 = xp1[(h + 1) * 64 + 32 + l31];
            v8h s00 = dupscalar(u00), s01 = dupscalar(u01);
            v8h s10 = dupscalar(u10), s11 = dupscalar(u11);
            v8h b000 = s00 * xv[0][0][0];
            acc[0][0][0] = MFMA32(a00, b000, acc[0][0][0]);
            acc[0][1][0] = MFMA32(a10, b000, acc[0][1][0]);
            v8h b010 = s01 * xv[0][1][0];
            acc[0][0][1] = MFMA32(a00, b010, acc[0][0][1]);
            acc[0][1][1] = MFMA32(a10, b010, acc[0][1][1]);
            v8h b100 = s10 * xv[1][0][0];
            acc[1][0][0] = MFMA32(a00, b100, acc[1][0][0]);
            acc[1][1][0] = MFMA32(a10, b100, acc[1][1][0]);
            v8h b110 = s11 * xv[1][1][0];
            acc[1][0][1] = MFMA32(a00, b110, acc[1][0][1]);
            acc[1][1][1] = MFMA32(a10, b110, acc[1][1][1]);
            v8h b001 = s00 * xv[0][0][1];
            acc[0][0][0] = MFMA32(a01, b001, acc[0][0][0]);
            acc[0][1][0] = MFMA32(a11, b001, acc[0][1][0]);
            v8h b011 = s01 * xv[0][1][1];
            acc[0][0][1] = MFMA32(a01, b011, acc[0][0][1]);
            acc[0][1][1] = MFMA32(a11, b011, acc[0][1][1]);
            v8h b101 = s10 * xv[1][0][1];
            acc[1][0][0] = MFMA32(a01, b101, acc[1][0][0]);
            acc[1][1][0] = MFMA32(a11, b101, acc[1][1][0]);
            v8h b111 = s11 * xv[1][1][1];
            acc[1][0][1] = MFMA32(a01, b111, acc[1][0][1]);
            acc[1][1][1] = MFMA32(a11, b111, acc[1][1][1]);
        }
        // peeled last h = 31
        v8h s00 = dupscalar(nu00), s01 = dupscalar(nu01);
        v8h s10 = dupscalar(nu10), s11 = dupscalar(nu11);
        v8h b000 = s00 * xv[0][0][0];
        acc[0][0][0] = MFMA32(na00, b000, acc[0][0][0]);
        acc[0][1][0] = MFMA32(na10, b000, acc[0][1][0]);
        v8h b010 = s01 * xv[0][1][0];
        acc[0][0][1] = MFMA32(na00, b010, acc[0][0][1]);
        acc[0][1][1] = MFMA32(na10, b010, acc[0][1][1]);
        v8h b100 = s10 * xv[1][0][0];
        acc[1][0][0] = MFMA32(na00, b100, acc[1][0][0]);
        acc[1][1][0] = MFMA32(na10, b100, acc[1][1][0]);
        v8h b110 = s11 * xv[1][1][0];
        acc[1][0][1] = MFMA32(na00, b110, acc[1][0][1]);
        acc[1][1][1] = MFMA32(na10, b110, acc[1][1][1]);
        v8h b001 = s00 * xv[0][0][1];
        acc[0][0][0] = MFMA32(na01, b001, acc[0][0][0]);
        acc[0][1][0] = MFMA32(na11, b001, acc[0][1][0]);
        v8h b011 = s01 * xv[0][1][1];
        acc[0][0][1] = MFMA32(na01, b011, acc[0][0][1]);
        acc[0][1][1] = MFMA32(na11, b011, acc[0][1][1]);
        v8h b101 = s10 * xv[1][0][1];
        acc[1][0][0] = MFMA32(na01, b101, acc[1][0][0]);
        acc[1][1][0] = MFMA32(na11, b101, acc[1][1][0]);
        v8h b111 = s11 * xv[1][1][1];
        acc[1][0][1] = MFMA32(na01, b111, acc[1][0][1]);
        acc[1][1][1] = MFMA32(na11, b111, acc[1][1][1]);
    }

    // ---- epilogue 0 ----
    if (rw == 0) {
        // rows 0..63 -> h1S (u16) for both batches
        #pragma unroll
        for (int lb = 0; lb < 2; ++lb)
            #pragma unroll
            for (int rt = 0; rt < 2; ++rt)
                #pragma unroll
                for (int reg = 0; reg < 16; ++reg) {
                    int row = rt * 32 + (reg & 3) + 8 * (reg >> 2) + 4 * hi;
                    float bias = biasLds[row];
                    float v0 = acc[lb][rt][0][reg] + bias;
                    float v1 = acc[lb][rt][1][reg] + bias;
                    v0 = v0 > 0.0f ? v0 : 0.0f;
                    v1 = v1 > 0.0f ? v1 : 0.0f;
                    h1S[lb0 + lb][row * 64 + l31]      = __builtin_bit_cast(uint16_t, (_Float16)v0);
                    h1S[lb0 + lb][row * 64 + 32 + l31] = __builtin_bit_cast(uint16_t, (_Float16)v1);
                }
    } else {
        // rows 64..127 -> out[b][row-64]
        #pragma unroll
        for (int lb = 0; lb < 2; ++lb)
            #pragma unroll
            for (int rt = 0; rt < 2; ++rt)
                #pragma unroll
                for (int reg = 0; reg < 16; ++reg) {
                    int grow = 64 + rt * 32 + (reg & 3) + 8 * (reg >> 2) + 4 * hi;
                    float bias = biasLds[grow];
                    float v0 = acc[lb][rt][0][reg] + bias;
                    float v1 = acc[lb][rt][1][reg] + bias;
                    float s = (v0 > 0.0f ? v0 : 0.0f) + (v1 > 0.0f ? v1 : 0.0f);
                    s += __shfl_xor(s, 1);
                    s += __shfl_xor(s, 2);
                    s += __shfl_xor(s, 4);
                    s += __shfl_xor(s, 8);
                    s += __shfl_xor(s, 16);
                    if (l31 == 0) out[(bb + lb0 + lb) * OUTC + (grow - 64)] = s;
                }
    }
    __syncthreads();

    // ================= layer 1 (H=64) =================
    #pragma unroll
    for (int lb = 0; lb < 2; ++lb)
        #pragma unroll
        for (int rt = 0; rt < 2; ++rt)
            #pragma unroll
            for (int c = 0; c < 2; ++c) acc[lb][rt][c] = (v16f)0.0f;
    {
        const _Float16* Wp = Wsw + L0_ELEMS + (size_t)rw * 1024 + (size_t)lane * 8;
        const uint16_t* hp0 = &h1S[lb0][0];
        const uint16_t* hp1 = &h1S[lb0 + 1][0];
        v8h na00 = *(const v8h*)(Wp);
        v8h na10 = *(const v8h*)(Wp + 512);
        v8h na01 = *(const v8h*)(Wp + 2048);
        v8h na11 = *(const v8h*)(Wp + 2560);
        uint32_t nu00 = hp0[l31], nu01 = hp0[32 + l31];
        uint32_t nu10 = hp1[l31], nu11 = hp1[32 + l31];
        #pragma unroll 2
        for (int h = 0; h < 63; ++h) {
            v8h a00 = na00, a10 = na10, a01 = na01, a11 = na11;
            uint32_t u00 = nu00, u01 = nu01, u10 = nu10, u11 = nu11;
            Wp += 4096;
            na00 = *(const v8h*)(Wp);
            na10 = *(const v8h*)(Wp + 512);
            na01 = *(const v8h*)(Wp + 2048);
            na11 = *(const v8h*)(Wp + 2560);
            nu00 = hp0[(h + 1) * 64 + l31];
            nu01 = hp0[(h + 1) * 64 + 32 + l31];
            nu10 = hp1[(h + 1) * 64 + l31];
            nu11 = hp1[(h + 1) * 64 + 32 + l31];
            v8h s00 = dupscalar(u00), s01 = dupscalar(u01);
            v8h s10 = dupscalar(u10), s11 = dupscalar(u11);
            v8h b000 = s00 * xv[0][0][0];
            acc[0][0][0] = MFMA32(a00, b000, acc[0][0][0]);
            acc[0][1][0] = MFMA32(a10, b000, acc[0][1][0]);
            v8h b010 = s01 * xv[0][1][0];
            acc[0][0][1] = MFMA32(a00, b010, acc[0][0][1]);
            acc[0][1][1] = MFMA32(a10, b010, acc[0][1][1]);
            v8h b100 = s10 * xv[1][0][0];
            acc[1][0][0] = MFMA32(a00, b100, acc[1][0][0]);
            acc[1][1][0] = MFMA32(a10, b100, acc[1][1][0]);
            v8h b110 = s11 * xv[1][1][0];
            acc[1][0][1] = MFMA32(a00, b110, acc[1][0][1]);
            acc[1][1][1] = MFMA32(a10, b110, acc[1][1][1]);
            v8h b001 = s00 * xv[0][0][1];
            acc[0][0][0] = MFMA32(a01, b001, acc[0][0][0]);
            acc[0][1][0] = MFMA32(a11, b001, acc[0][1][0]);
            v8h b011 = s01 * xv[0][1][1];
            acc[0][0][1] = MFMA32(a01, b011, acc[0][0][1]);
            acc[0][1][1] = MFMA32(a11, b011, acc[0][1][1]);
            v8h b101 = s10 * xv[1][0][1];
            acc[1][0][0] = MFMA32(a01, b101, acc[1][0][0]);
            acc[1][1][0] = MFMA32(a11, b101, acc[1][1][0]);
            v8h b111 = s11 * xv[1][1][1];
            acc[1][0][1] = MFMA32(a01, b111, acc[1][0][1]);
            acc[1][1][1] = MFMA32(a11, b111, acc[1][1][1]);
        }
        // peeled last h = 63
        v8h s00 = dupscalar(nu00), s01 = dupscalar(nu01);
        v8h s10 = dupscalar(nu10), s11 = dupscalar(nu11);
        v8h b000 = s00 * xv[0][0][0];
        acc[0][0][0] = MFMA32(na00, b000, acc[0][0][0]);
        acc[0][1][0] = MFMA32(na10, b000, acc[0][1][0]);
        v8h b010 = s01 * xv[0][1][0];
        acc[0][0][1] = MFMA32(na00, b010, acc[0][0][1]);
        acc[0][1][1] = MFMA32(na10, b010, acc[0][1][1]);
        v8h b100 = s10 * xv[1][0][0];
        acc[1][0][0] = MFMA32(na00, b100, acc[1][0][0]);
        acc[1][1][0] = MFMA32(na10, b100, acc[1][1][0]);
        v8h b110 = s11 * xv[1][1][0];
        acc[1][0][1] = MFMA32(na00, b110, acc[1][0][1]);
        acc[1][1][1] = MFMA32(na10, b110, acc[1][1][1]);
        v8h b001 = s00 * xv[0][0][1];
        acc[0][0][0] = MFMA32(na01, b001, acc[0][0][0]);
        acc[0][1][0] = MFMA32(na11, b001, acc[0][1][0]);
        v8h b011 = s01 * xv[0][1][1];
        acc[0][0][1] = MFMA32(na01, b011, acc[0][0][1]);
        acc[0][1][1] = MFMA32(na11, b011, acc[0][1][1]);
        v8h b101 = s10 * xv[1][0][1];
        acc[1][0][0] = MFMA32(na01, b101, acc[1][0][0]);
        acc[1][1][0] = MFMA32(na11, b101, acc[1][1][0]);
        v8h b111 = s11 * xv[1][1][1];
        acc[1][0][1] = MFMA32(na01, b111, acc[1][0][1]);
        acc[1][1][1] = MFMA32(na11, b111, acc[1][1][1]);
    }

    // ---- epilogue 1: all 128 rows -> out[b][64 + row] ----
    #pragma unroll
    for (int lb = 0; lb < 2; ++lb)
        #pragma unroll
        for (int rt = 0; rt < 2; ++rt)
            #pragma unroll
            for (int reg = 0; reg < 16; ++reg) {
                int grow = rw * 64 + rt * 32 + (reg & 3) + 8 * (reg >> 2) + 4 * hi;
                float bias = biasLds[128 + grow];
                float v0 = acc[lb][rt][0][reg] + bias;
                float v1 = acc[lb][rt][1][reg] + bias;
                float s = (v0 > 0.0f ? v0 : 0.0f) + (v1 > 0.0f ? v1 : 0.0f);
                s += __shfl_xor(s, 1);
                s += __shfl_xor(s, 2);
                s += __shfl_xor(s, 4);
                s += __shfl_xor(s, 8);
                s += __shfl_xor(s, 16);
                if (l31 == 0) out[(bb + lb0 + lb) * OUTC + 64 + grow] = s;
            }
}

extern "C" void kernel_launch(void* const* d_in, const int* in_sizes, int n_in,
                              void* d_out, int out_size, void* d_ws, size_t ws_size,
                              hipStream_t stream) {
    const float* X  = (const float*)d_in[0];
    const float* W0 = (const float*)d_in[1];
    const float* b0 = (const float*)d_in[2];
    const float* W1 = (const float*)d_in[3];
    const float* b1 = (const float*)d_in[4];
    float* out = (float*)d_out;
    _Float16* wsw = (_Float16*)d_ws;  // 768 KB

    int nconv = (L0_ELEMS + L1_ELEMS) / 8;  // 49152 threads
    convert_w_kernel<<<(nconv + 255) / 256, 256, 0, stream>>>(W0, W1, wsw);
    cin_kernel<<<512, 256, 0, stream>>>(X, b0, b1, wsw, out);
}